// Round 1
// baseline (879.786 us; speedup 1.0000x reference)
//
#include <hip/hip_runtime.h>

#define BB 16384
#define DD 256

typedef _Float16 f16;
typedef _Float16 h8 __attribute__((ext_vector_type(8)));
typedef float v4f __attribute__((ext_vector_type(4)));

#define MFMA(a,b,c) __builtin_amdgcn_mfma_f32_16x16x32_f16((a),(b),(c),0,0,0)

__device__ __forceinline__ float sigm(float x){ return 1.0f/(1.0f + __expf(-x)); }
// robust tanh via exp; handles +/-inf without NaN
__device__ __forceinline__ float tanh_f(float x){ float e = __expf(2.0f*x); return 1.0f - 2.0f/(e + 1.0f); }

// Swizzled LDS A-fragment read: 16B granule XOR'd with row&7 to avoid bank conflicts.
__device__ __forceinline__ h8 ldsA(const f16* s, int row, int stride, int k0){
  int g = (k0 >> 3) ^ (row & 7);
  return *reinterpret_cast<const h8*>(s + row*stride + g*8);
}

// ---------------- k0a: f16 weight conversions ----------------
// regions (elements): wih_sel 768*512 | wv 256*256 | w2 768*256 | wzr1 512*256 | wh1 256*256
__global__ __launch_bounds__(512) void k0_convert(
    const float* __restrict__ Wih, const float* __restrict__ vW,
    const float* __restrict__ zW, const float* __restrict__ rW, const float* __restrict__ hW,
    f16* __restrict__ wih16, f16* __restrict__ wv16, f16* __restrict__ w2,
    f16* __restrict__ wzr1, f16* __restrict__ wh1)
{
  int idx = blockIdx.x*512 + threadIdx.x;
  if (idx < 393216){
    int j = idx >> 9, k = idx & 511;
    int sj = (j < 256) ? j : j + 256;  // packed rows: i(0..255), g(512..767), o(768..1023)
    wih16[idx] = (f16)Wih[sj*512 + k];
    return;
  }
  idx -= 393216;
  if (idx < 65536){ wv16[idx] = (f16)vW[idx]; return; }
  idx -= 65536;
  if (idx < 196608){
    int j = idx >> 8, k = idx & 255;
    float v = (j < 256) ? zW[j*512 + 256 + k]
            : (j < 512) ? rW[(j-256)*512 + 256 + k]
                        : hW[(j-512)*512 + 256 + k];
    w2[idx] = (f16)v;
    return;
  }
  idx -= 196608;
  if (idx < 131072){
    int j = idx >> 8, k = idx & 255;
    wzr1[idx] = (f16)((j < 256) ? zW[j*512 + k] : rW[(j-256)*512 + k]);
    return;
  }
  idx -= 131072;
  {
    int j = idx >> 8, k = idx & 255;
    wh1[idx] = (f16)hW[j*512 + k];
  }
}

// ---------------- k0b: Wqk'[d][e] = sum_j qW[j,e]*kW[j,d]  (B-operand for Qk GEMM) ----------------
__global__ __launch_bounds__(256) void k0_wqkt(const float* __restrict__ qW, const float* __restrict__ kW,
                                               f16* __restrict__ wqkt)
{
  int d = blockIdx.x, e = threadIdx.x;
  float acc = 0.f;
  for (int j = 0; j < 256; ++j) acc += qW[j*256 + e] * kW[j*256 + d];
  wqkt[d*256 + e] = (f16)acc;
}

// ---------------- k0c: bqk[e]=qb@kW[:,e], u[e]=kb@qW[:,e], c0=qb.kb ----------------
__global__ __launch_bounds__(256) void k0_misc(const float* __restrict__ qW, const float* __restrict__ kW,
                                               const float* __restrict__ qb, const float* __restrict__ kb,
                                               float* __restrict__ bqk, float* __restrict__ u, float* __restrict__ c0)
{
  int e = threadIdx.x;
  float a = 0.f, b = 0.f;
  for (int j = 0; j < 256; ++j){ a += qb[j]*kW[j*256 + e]; b += kb[j]*qW[j*256 + e]; }
  bqk[e] = a; u[e] = b;
  if (e == 0){ float c = 0.f; for (int j = 0; j < 256; ++j) c += qb[j]*kb[j]; c0[0] = c; }
}

// ---------------- k1: frontend (norms -> W_t -> LSTM -> O' -> Qk, sQ) ----------------
// 512 blocks x 512 threads, TB=32 batch rows per block.
__global__ __launch_bounds__(512) void k1_frontend(
    const float* __restrict__ O_t, const float* __restrict__ O_prev,
    const float* __restrict__ mlpW, const float* __restrict__ mlpB,
    const float* __restrict__ bih, const float* __restrict__ bhh,
    const f16* __restrict__ wih16, const f16* __restrict__ wqkt,
    const float* __restrict__ bqk, const float* __restrict__ u, const float* __restrict__ c0,
    float* __restrict__ wt_out, float* __restrict__ Qk, float* __restrict__ sQ)
{
  __shared__ f16 xs[32*512];   // x = [O_prev | O_t*W_t], swizzled
  __shared__ f16 o1[32*256];   // O_t_prime f16, swizzled
  const int t   = threadIdx.x;
  const int b0  = blockIdx.x * 32;
  const int r   = t >> 4, sub = t & 15;
  const int b   = b0 + r;

  // ---- phase A: per-row stats, W_t, build x ----
  {
    float ot[16], op[16];
    float stt = 0.f, spp = 0.f, stp = 0.f;
    const float* pt = O_t    + b*DD + sub*16;
    const float* pp = O_prev + b*DD + sub*16;
#pragma unroll
    for (int i = 0; i < 4; ++i){
      float4 a = *reinterpret_cast<const float4*>(pt + i*4);
      float4 c = *reinterpret_cast<const float4*>(pp + i*4);
      ot[i*4+0]=a.x; ot[i*4+1]=a.y; ot[i*4+2]=a.z; ot[i*4+3]=a.w;
      op[i*4+0]=c.x; op[i*4+1]=c.y; op[i*4+2]=c.z; op[i*4+3]=c.w;
      stt += a.x*a.x + a.y*a.y + a.z*a.z + a.w*a.w;
      spp += c.x*c.x + c.y*c.y + c.z*c.z + c.w*c.w;
      stp += a.x*c.x + a.y*c.y + a.z*c.z + a.w*c.w;
    }
#pragma unroll
    for (int off = 8; off >= 1; off >>= 1){
      stt += __shfl_xor(stt, off);
      spp += __shfl_xor(spp, off);
      stp += __shfl_xor(stp, off);
    }
    float n_t = sqrtf(stt), n_p = sqrtf(spp);
    float r_d = sqrtf(fmaxf(stt - 2.f*stp + spp, 0.f));
    float r_a = stp / (n_t*n_p + 1e-6f);

    // x[r][0:256] = O_prev
    h8 h0, h1;
#pragma unroll
    for (int j = 0; j < 8; ++j){ h0[j] = (f16)op[j]; h1[j] = (f16)op[8+j]; }
    *reinterpret_cast<h8*>(&xs[r*512 + (((sub*2  ) ^ (r&7)))*8]) = h0;
    *reinterpret_cast<h8*>(&xs[r*512 + (((sub*2+1) ^ (r&7)))*8]) = h1;

    // W_t and x[r][256:512] = O_t * W_t
    float wts[16];
#pragma unroll
    for (int i = 0; i < 16; ++i){
      int d = sub*16 + i;
      float xv = mlpW[d*3+0]*n_t + mlpW[d*3+1]*r_d + mlpW[d*3+2]*r_a + mlpB[d];
      wts[i] = 0.5f*(tanh_f(xv) + 1.0f);
    }
#pragma unroll
    for (int i = 0; i < 16; i += 4){
      float4 v; v.x=wts[i]; v.y=wts[i+1]; v.z=wts[i+2]; v.w=wts[i+3];
      *reinterpret_cast<float4*>(wt_out + (size_t)b*DD + sub*16 + i) = v;
    }
    h8 u0, u1;
#pragma unroll
    for (int j = 0; j < 8; ++j){ u0[j] = (f16)(ot[j]*wts[j]); u1[j] = (f16)(ot[8+j]*wts[8+j]); }
    *reinterpret_cast<h8*>(&xs[r*512 + (((32 + sub*2  ) ^ (r&7)))*8]) = u0;
    *reinterpret_cast<h8*>(&xs[r*512 + (((32 + sub*2+1) ^ (r&7)))*8]) = u1;
  }
  __syncthreads();

  const int w = t >> 6, l = t & 63;
  const int lr = l & 15, lk = l >> 4;

  // ---- phase B: gates GEMM [32 x 768], K=512 (i,g,o only) ----
  {
    v4f acc[3][2][2];
#pragma unroll
    for (int g = 0; g < 3; ++g)
#pragma unroll
      for (int dt = 0; dt < 2; ++dt)
#pragma unroll
        for (int mt = 0; mt < 2; ++mt) acc[g][dt][mt] = (v4f){0.f,0.f,0.f,0.f};

    for (int ks = 0; ks < 16; ++ks){
      h8 A0 = ldsA(xs, lr,      512, ks*32 + lk*8);
      h8 A1 = ldsA(xs, 16 + lr, 512, ks*32 + lk*8);
#pragma unroll
      for (int dt = 0; dt < 2; ++dt){
        const int dbase = (w*2 + dt)*16;
#pragma unroll
        for (int g = 0; g < 3; ++g){
          const int jrow = g*256 + dbase + lr;
          h8 Bf = *reinterpret_cast<const h8*>(wih16 + jrow*512 + ks*32 + lk*8);
          acc[g][dt][0] = MFMA(A0, Bf, acc[g][dt][0]);
          acc[g][dt][1] = MFMA(A1, Bf, acc[g][dt][1]);
        }
      }
    }
#pragma unroll
    for (int dt = 0; dt < 2; ++dt){
      const int d  = (w*2 + dt)*16 + lr;
      const float bi = bih[d]       + bhh[d];
      const float bg = bih[512 + d] + bhh[512 + d];
      const float bo = bih[768 + d] + bhh[768 + d];
#pragma unroll
      for (int mt = 0; mt < 2; ++mt){
#pragma unroll
        for (int q = 0; q < 4; ++q){
          const int row = mt*16 + lk*4 + q;
          float iv = sigm(acc[0][dt][mt][q] + bi);
          float gv = tanh_f(acc[1][dt][mt][q] + bg);
          float ov = sigm(acc[2][dt][mt][q] + bo);
          float o  = ov * tanh_f(iv*gv);
          int g = ((d >> 3) ^ (row & 7));
          o1[row*256 + g*8 + (d & 7)] = (f16)o;
        }
      }
    }
  }
  __syncthreads();

  // ---- sQ = O'.u + c0 ----
  {
    float s = 0.f;
#pragma unroll
    for (int i = 0; i < 16; ++i){
      int dd = sub*16 + i;
      int g = ((dd >> 3) ^ (r & 7));
      s += (float)o1[r*256 + g*8 + (dd & 7)] * u[dd];
    }
#pragma unroll
    for (int off = 8; off >= 1; off >>= 1) s += __shfl_xor(s, off);
    if (sub == 0) sQ[b] = s + c0[0];
  }

  // ---- phase C: Qk GEMM [32 x 256], K=256 ----
  {
    v4f acc[2][2];
#pragma unroll
    for (int nt = 0; nt < 2; ++nt)
#pragma unroll
      for (int mt = 0; mt < 2; ++mt) acc[nt][mt] = (v4f){0.f,0.f,0.f,0.f};

    for (int ks = 0; ks < 8; ++ks){
      h8 A0 = ldsA(o1, lr,      256, ks*32 + lk*8);
      h8 A1 = ldsA(o1, 16 + lr, 256, ks*32 + lk*8);
#pragma unroll
      for (int nt = 0; nt < 2; ++nt){
        const int dcol = (w*2 + nt)*16 + lr;
        h8 Bf = *reinterpret_cast<const h8*>(wqkt + dcol*256 + ks*32 + lk*8);
        acc[nt][0] = MFMA(A0, Bf, acc[nt][0]);
        acc[nt][1] = MFMA(A1, Bf, acc[nt][1]);
      }
    }
#pragma unroll
    for (int nt = 0; nt < 2; ++nt){
      const int dcol = (w*2 + nt)*16 + lr;
      const float bq = bqk[dcol];
#pragma unroll
      for (int mt = 0; mt < 2; ++mt){
#pragma unroll
        for (int q = 0; q < 4; ++q){
          const int row = mt*16 + lk*4 + q;
          Qk[(size_t)(b0 + row)*DD + dcol] = acc[nt][mt][q] + bq;
        }
      }
    }
  }
}

// ---------------- k2a: attention (scores/softmax/mbar/O_up) + per-b z2r2h2 ----------------
// 1024 blocks x 512 threads, TB=16 batch rows, dyn LDS 116224 B
__global__ __launch_bounds__(512) void k2a_attn(
    const float* __restrict__ mem, const float* __restrict__ Qk, const float* __restrict__ sQ,
    const f16* __restrict__ wv16, const float* __restrict__ v_b,
    const f16* __restrict__ w2, float* __restrict__ out, f16* __restrict__ z2r2h2)
{
  extern __shared__ char smem[];
  f16*   ms     = (f16*)  (smem);            // [160][256] f16, swizzled
  float* qks    = (float*)(smem + 81920);    // [16][256]
  float* scores = (float*)(smem + 98304);    // [160]
  float* attns  = (float*)(smem + 98944);    // [160]
  f16*   mbar   = (f16*)  (smem + 99584);    // [16][256] swizzled
  f16*   oup    = (f16*)  (smem + 107776);   // [16][256] swizzled

  const int t  = threadIdx.x;
  const int b0 = blockIdx.x * 16;
  const int sub = t & 15;

  { // load Qk tile
    const float4* src = reinterpret_cast<const float4*>(Qk + (size_t)b0*DD);
    float4* dst = reinterpret_cast<float4*>(qks);
    dst[t] = src[t];
    dst[t + 512] = src[t + 512];
  }
  __syncthreads();

  // load memory tile (f16, swizzled) + score partials
  for (int p = 0; p < 5; ++p){
    const int rl = p*32 + (t >> 4);
    const int bl = rl / 10;
    const float* srcp = mem + ((size_t)(b0*10 + rl))*DD + sub*16;
    const float* qrow = qks + bl*DD + sub*16;
    float s = 0.f;
    f16 hv[16];
#pragma unroll
    for (int i = 0; i < 4; ++i){
      float4 v = *reinterpret_cast<const float4*>(srcp + i*4);
      float4 q = *reinterpret_cast<const float4*>(qrow + i*4);
      s += v.x*q.x + v.y*q.y + v.z*q.z + v.w*q.w;
      hv[i*4+0]=(f16)v.x; hv[i*4+1]=(f16)v.y; hv[i*4+2]=(f16)v.z; hv[i*4+3]=(f16)v.w;
    }
    h8 h0, h1;
#pragma unroll
    for (int j = 0; j < 8; ++j){ h0[j]=hv[j]; h1[j]=hv[8+j]; }
    *reinterpret_cast<h8*>(&ms[rl*256 + (((sub*2  ) ^ (rl&7)))*8]) = h0;
    *reinterpret_cast<h8*>(&ms[rl*256 + (((sub*2+1) ^ (rl&7)))*8]) = h1;
#pragma unroll
    for (int off = 8; off >= 1; off >>= 1) s += __shfl_xor(s, off);
    if (sub == 0) scores[rl] = s;
  }
  __syncthreads();

  if (t < 16){ // softmax over 10
    const float sq = sQ[b0 + t];
    float e[10]; float mx = -1e30f;
#pragma unroll
    for (int m = 0; m < 10; ++m){ e[m] = (scores[t*10 + m] + sq)*0.0625f; mx = fmaxf(mx, e[m]); }
    float ss = 0.f;
#pragma unroll
    for (int m = 0; m < 10; ++m){ e[m] = __expf(e[m] - mx); ss += e[m]; }
    float inv = 1.f/ss;
#pragma unroll
    for (int m = 0; m < 10; ++m) attns[t*10 + m] = e[m]*inv;
  }
  __syncthreads();

  { // mbar = sum_m attn*mem
    const int rr = t >> 5;
    const int s5 = t & 31;
    float a[8];
#pragma unroll
    for (int i = 0; i < 8; ++i) a[i] = 0.f;
#pragma unroll
    for (int m = 0; m < 10; ++m){
      const int row = rr*10 + m;
      const float wg = attns[row];
      h8 h = *reinterpret_cast<const h8*>(&ms[row*256 + ((s5 ^ (row&7)))*8]);
#pragma unroll
      for (int i = 0; i < 8; ++i) a[i] += wg*(float)h[i];
    }
    h8 hb;
#pragma unroll
    for (int i = 0; i < 8; ++i) hb[i] = (f16)a[i];
    *reinterpret_cast<h8*>(&mbar[rr*256 + ((s5 ^ (rr&7)))*8]) = hb;
  }
  __syncthreads();

  const int w = t >> 6, l = t & 63, lr = l & 15, lk = l >> 4;

  { // O_up = mbar @ vW^T + v_b ; write out0/out2/out1[:,9,:]
    v4f acc[2]; acc[0] = (v4f){0.f,0.f,0.f,0.f}; acc[1] = (v4f){0.f,0.f,0.f,0.f};
    for (int ks = 0; ks < 8; ++ks){
      h8 A = ldsA(mbar, lr, 256, ks*32 + lk*8);
#pragma unroll
      for (int nt = 0; nt < 2; ++nt){
        const int col = (w*2 + nt)*16 + lr;
        h8 Bf = *reinterpret_cast<const h8*>(wv16 + col*256 + ks*32 + lk*8);
        acc[nt] = MFMA(A, Bf, acc[nt]);
      }
    }
#pragma unroll
    for (int nt = 0; nt < 2; ++nt){
      const int col = (w*2 + nt)*16 + lr;
      const float vb = v_b[col];
#pragma unroll
      for (int q = 0; q < 4; ++q){
        const int row = lk*4 + q;
        const int bb = b0 + row;
        float v = acc[nt][q] + vb;
        out[(size_t)bb*DD + col] = v;                                   // O_up (out 0)
        out[(size_t)11*BB*DD + (size_t)bb*DD + col] = v;                // O_up (out 2)
        out[(size_t)BB*DD + ((size_t)bb*10 + 9)*DD + col] = v;          // memory_new[:,9,:]
        int g = ((col >> 3) ^ (row & 7));
        oup[row*256 + g*8 + (col & 7)] = (f16)v;
      }
    }
  }
  __syncthreads();

  { // z2r2h2 = O_up @ [zW2;rW2;hW2]^T  (no bias here)
    v4f acc[6];
#pragma unroll
    for (int j = 0; j < 6; ++j) acc[j] = (v4f){0.f,0.f,0.f,0.f};
    for (int ks = 0; ks < 8; ++ks){
      h8 A = ldsA(oup, lr, 256, ks*32 + lk*8);
#pragma unroll
      for (int j = 0; j < 6; ++j){
        const int ntg = w*6 + j;
        h8 Bf = *reinterpret_cast<const h8*>(w2 + (ntg*16 + lr)*256 + ks*32 + lk*8);
        acc[j] = MFMA(A, Bf, acc[j]);
      }
    }
#pragma unroll
    for (int j = 0; j < 6; ++j){
      const int colg = (w*6 + j)*16 + lr;
#pragma unroll
      for (int q = 0; q < 4; ++q){
        const int row = lk*4 + q;
        z2r2h2[((size_t)(b0 + row))*768 + colg] = (f16)acc[j][q];
      }
    }
  }
}

// ---------------- k2b: memory update (z,r GEMMs -> r*mem -> h GEMM -> combine+shift) ----------------
// 2048 blocks x 512 threads, TB=8 batch rows (80 mem rows), dyn LDS 81920 B
__global__ __launch_bounds__(512) void k2b_update(
    const float* __restrict__ mem, const f16* __restrict__ wzr1, const f16* __restrict__ wh1,
    const f16* __restrict__ z2r2h2, const float* __restrict__ z_b, const float* __restrict__ r_b,
    const float* __restrict__ h_b, float* __restrict__ out1)
{
  extern __shared__ char smem[];
  f16* ms = (f16*)smem;            // [80][256] swizzled
  f16* a2 = (f16*)(smem + 40960);  // [80][256] swizzled

  const int t  = threadIdx.x;
  const int b0 = blockIdx.x * 8;
  const int sub = t & 15;

  for (int p = 0; p < 3; ++p){
    const int rl = p*32 + (t >> 4);
    if (rl < 80){
      const float* srcp = mem + ((size_t)(b0*10 + rl))*DD + sub*16;
      f16 hv[16];
#pragma unroll
      for (int i = 0; i < 4; ++i){
        float4 v = *reinterpret_cast<const float4*>(srcp + i*4);
        hv[i*4+0]=(f16)v.x; hv[i*4+1]=(f16)v.y; hv[i*4+2]=(f16)v.z; hv[i*4+3]=(f16)v.w;
      }
      h8 h0, h1;
#pragma unroll
      for (int j = 0; j < 8; ++j){ h0[j]=hv[j]; h1[j]=hv[8+j]; }
      *reinterpret_cast<h8*>(&ms[rl*256 + (((sub*2  ) ^ (rl&7)))*8]) = h0;
      *reinterpret_cast<h8*>(&ms[rl*256 + (((sub*2+1) ^ (rl&7)))*8]) = h1;
    }
  }
  __syncthreads();

  const int w = t >> 6, l = t & 63, lr = l & 15, lk = l >> 4;
  float zreg[5][2][4];

  { // z GEMM
    v4f acc[5][2];
#pragma unroll
    for (int mt = 0; mt < 5; ++mt){ acc[mt][0]=(v4f){0.f,0.f,0.f,0.f}; acc[mt][1]=(v4f){0.f,0.f,0.f,0.f}; }
    for (int ks = 0; ks < 8; ++ks){
      h8 A[5];
#pragma unroll
      for (int mt = 0; mt < 5; ++mt) A[mt] = ldsA(ms, mt*16 + lr, 256, ks*32 + lk*8);
#pragma unroll
      for (int nt = 0; nt < 2; ++nt){
        const int jrow = (w*2 + nt)*16 + lr;
        h8 Bf = *reinterpret_cast<const h8*>(wzr1 + jrow*256 + ks*32 + lk*8);
#pragma unroll
        for (int mt = 0; mt < 5; ++mt) acc[mt][nt] = MFMA(A[mt], Bf, acc[mt][nt]);
      }
    }
#pragma unroll
    for (int mt = 0; mt < 5; ++mt)
#pragma unroll
      for (int nt = 0; nt < 2; ++nt){
        const int col = (w*2 + nt)*16 + lr;
#pragma unroll
        for (int q = 0; q < 4; ++q){
          const int row = mt*16 + lk*4 + q;
          const int bb = b0 + row/10;
          float x = acc[mt][nt][q] + (float)z2r2h2[(size_t)bb*768 + col] + z_b[col];
          zreg[mt][nt][q] = sigm(x);
        }
      }
  }

  { // r GEMM -> a2 = r*mem
    v4f acc[5][2];
#pragma unroll
    for (int mt = 0; mt < 5; ++mt){ acc[mt][0]=(v4f){0.f,0.f,0.f,0.f}; acc[mt][1]=(v4f){0.f,0.f,0.f,0.f}; }
    for (int ks = 0; ks < 8; ++ks){
      h8 A[5];
#pragma unroll
      for (int mt = 0; mt < 5; ++mt) A[mt] = ldsA(ms, mt*16 + lr, 256, ks*32 + lk*8);
#pragma unroll
      for (int nt = 0; nt < 2; ++nt){
        const int jrow = 256 + (w*2 + nt)*16 + lr;
        h8 Bf = *reinterpret_cast<const h8*>(wzr1 + jrow*256 + ks*32 + lk*8);
#pragma unroll
        for (int mt = 0; mt < 5; ++mt) acc[mt][nt] = MFMA(A[mt], Bf, acc[mt][nt]);
      }
    }
#pragma unroll
    for (int mt = 0; mt < 5; ++mt)
#pragma unroll
      for (int nt = 0; nt < 2; ++nt){
        const int col = (w*2 + nt)*16 + lr;
#pragma unroll
        for (int q = 0; q < 4; ++q){
          const int row = mt*16 + lk*4 + q;
          const int bb = b0 + row/10;
          float x = acc[mt][nt][q] + (float)z2r2h2[(size_t)bb*768 + 256 + col] + r_b[col];
          float rv = sigm(x);
          int g = ((col >> 3) ^ (row & 7));
          float mv = (float)ms[row*256 + g*8 + (col & 7)];
          a2[row*256 + g*8 + (col & 7)] = (f16)(rv*mv);
        }
      }
  }
  __syncthreads();

  { // h GEMM -> m_tilde -> memory_new (shifted write)
    v4f acc[5][2];
#pragma unroll
    for (int mt = 0; mt < 5; ++mt){ acc[mt][0]=(v4f){0.f,0.f,0.f,0.f}; acc[mt][1]=(v4f){0.f,0.f,0.f,0.f}; }
    for (int ks = 0; ks < 8; ++ks){
      h8 A[5];
#pragma unroll
      for (int mt = 0; mt < 5; ++mt) A[mt] = ldsA(a2, mt*16 + lr, 256, ks*32 + lk*8);
#pragma unroll
      for (int nt = 0; nt < 2; ++nt){
        const int jrow = (w*2 + nt)*16 + lr;
        h8 Bf = *reinterpret_cast<const h8*>(wh1 + jrow*256 + ks*32 + lk*8);
#pragma unroll
        for (int mt = 0; mt < 5; ++mt) acc[mt][nt] = MFMA(A[mt], Bf, acc[mt][nt]);
      }
    }
#pragma unroll
    for (int mt = 0; mt < 5; ++mt)
#pragma unroll
      for (int nt = 0; nt < 2; ++nt){
        const int col = (w*2 + nt)*16 + lr;
#pragma unroll
        for (int q = 0; q < 4; ++q){
          const int row = mt*16 + lk*4 + q;
          const int bl = row/10;
          const int m  = row - bl*10;
          const int bb = b0 + bl;
          float mtld = tanh_f(acc[mt][nt][q] + (float)z2r2h2[(size_t)bb*768 + 512 + col] + h_b[col]);
          int g = ((col >> 3) ^ (row & 7));
          float mv = (float)ms[row*256 + g*8 + (col & 7)];
          float z = zreg[mt][nt][q];
          float res = z*mv + (1.f - z)*mtld;
          if (m > 0) out1[((size_t)bb*10 + (m-1))*DD + col] = res;
        }
      }
  }
}

extern "C" void kernel_launch(void* const* d_in, const int* in_sizes, int n_in,
                              void* d_out, int out_size, void* d_ws, size_t ws_size,
                              hipStream_t stream)
{
  (void)in_sizes; (void)n_in; (void)out_size; (void)ws_size;

  const float* O_t    = (const float*)d_in[0];
  const float* O_prev = (const float*)d_in[1];
  const float* mem    = (const float*)d_in[2];
  const float* mlpW   = (const float*)d_in[3];
  const float* mlpB   = (const float*)d_in[4];
  const float* Wih    = (const float*)d_in[5];
  // d_in[6] lstm_Whh unused (h0 = 0)
  const float* bih    = (const float*)d_in[7];
  const float* bhh    = (const float*)d_in[8];
  const float* qW     = (const float*)d_in[9];
  const float* qb     = (const float*)d_in[10];
  const float* kW     = (const float*)d_in[11];
  const float* kb     = (const float*)d_in[12];
  const float* vW     = (const float*)d_in[13];
  const float* vb     = (const float*)d_in[14];
  const float* zW     = (const float*)d_in[15];
  const float* zb     = (const float*)d_in[16];
  const float* rW     = (const float*)d_in[17];
  const float* rb     = (const float*)d_in[18];
  const float* hW     = (const float*)d_in[19];
  const float* hb     = (const float*)d_in[20];

  char* ws = (char*)d_ws;
  f16*   wih16 = (f16*)  (ws + 0);
  f16*   wqkt  = (f16*)  (ws + 786432);
  f16*   wv16  = (f16*)  (ws + 917504);
  f16*   w2    = (f16*)  (ws + 1048576);
  f16*   wzr1  = (f16*)  (ws + 1441792);
  f16*   wh1   = (f16*)  (ws + 1703936);
  float* bqk   = (float*)(ws + 1835008);
  float* u     = (float*)(ws + 1836032);
  float* c0    = (float*)(ws + 1837056);
  float* Qk    = (float*)(ws + 2097152);
  float* sQ    = (float*)(ws + 18874368);
  f16*   z2r2h2= (f16*)  (ws + 18939904);

  float* out    = (float*)d_out;
  float* wt_out = out + (size_t)12*BB*DD;
  float* out1   = out + (size_t)BB*DD;

  hipFuncSetAttribute((const void*)k2a_attn,  hipFuncAttributeMaxDynamicSharedMemorySize, 116224);
  hipFuncSetAttribute((const void*)k2b_update, hipFuncAttributeMaxDynamicSharedMemorySize, 81920);

  k0_convert<<<dim3(1664), dim3(512), 0, stream>>>(Wih, vW, zW, rW, hW, wih16, wv16, w2, wzr1, wh1);
  k0_wqkt  <<<dim3(256),  dim3(256), 0, stream>>>(qW, kW, wqkt);
  k0_misc  <<<dim3(1),    dim3(256), 0, stream>>>(qW, kW, qb, kb, bqk, u, c0);
  k1_frontend<<<dim3(512), dim3(512), 0, stream>>>(O_t, O_prev, mlpW, mlpB, bih, bhh,
                                                   wih16, wqkt, bqk, u, c0, wt_out, Qk, sQ);
  k2a_attn <<<dim3(1024), dim3(512), 116224, stream>>>(mem, Qk, sQ, wv16, vb, w2, out, z2r2h2);
  k2b_update<<<dim3(2048), dim3(512), 81920, stream>>>(mem, wzr1, wh1, z2r2h2, zb, rb, hb, out1);
}